// Round 6
// baseline (5794.180 us; speedup 1.0000x reference)
//
#include <hip/hip_runtime.h>
#include <hip/hip_fp16.h>
#include <cstddef>
#include <cstdint>

#define U_DIM 256
#define G_DIM 1024          // 4*U
#define T_DIM 512
#define B_DIM 64
#define TC    128           // timesteps per chunk
#define NCHUNK (T_DIM / TC)

// Weight residency split (32 groups of 8 k-values each = K=256).
// 256 threads/block, thread t owns hidden unit t = gate cols {t,t+256,t+512,t+768}.
#define NG_TOT 32
#define NG_REG 22           // groups  0..21 -> regs (22*4cols*4 = 352 VGPRs/thread)
#define NG_LDS 7            // groups 22..28 -> LDS (7*16 KB = 112 KB)
#define NG_STR 3            // groups 29..31 -> streamed from L2 each step (48 KB)

typedef _Float16 half2v __attribute__((ext_vector_type(2)));

__device__ __forceinline__ float fsig(float x) {
    return 1.0f / (1.0f + __expf(-x));
}
__device__ __forceinline__ float ftanh(float x) {
    return 2.0f * fsig(2.0f * x) - 1.0f;
}

// ---------------------------------------------------------------------------
// Pack U [256,1024] fp32 -> P: [32 groups][1024 cols] of uint4.
// P[g][n] holds f16(U[8g+0..8g+7][n]) packed 2-per-u32.
// ---------------------------------------------------------------------------
__global__ __launch_bounds__(256)
void pack_w(const float* __restrict__ U, uint4* __restrict__ P)
{
    const int idx = blockIdx.x * 256 + threadIdx.x;   // 0..32767
    const int g = idx >> 10;
    const int n = idx & 1023;
    uint vals[4];
    #pragma unroll
    for (int j = 0; j < 4; ++j) {
        const int k = g * 8 + j * 2;
        const __half a = __float2half_rn(U[(size_t)k * G_DIM + n]);
        const __half b = __float2half_rn(U[(size_t)(k + 1) * G_DIM + n]);
        const unsigned short ua = __builtin_bit_cast(unsigned short, a);
        const unsigned short ub = __builtin_bit_cast(unsigned short, b);
        vals[j] = (uint)ua | ((uint)ub << 16);
    }
    P[idx] = make_uint4(vals[0], vals[1], vals[2], vals[3]);
}

// 8 MACs: acc += sum_j f16(h)[j] * f16(w)[j]   (both packed 2-per-u32)
__device__ __forceinline__ float mac8(float acc, uint4 w, uint4 h)
{
#if __has_builtin(__builtin_amdgcn_fdot2)
    acc = __builtin_amdgcn_fdot2(__builtin_bit_cast(half2v, h.x),
                                 __builtin_bit_cast(half2v, w.x), acc, false);
    acc = __builtin_amdgcn_fdot2(__builtin_bit_cast(half2v, h.y),
                                 __builtin_bit_cast(half2v, w.y), acc, false);
    acc = __builtin_amdgcn_fdot2(__builtin_bit_cast(half2v, h.z),
                                 __builtin_bit_cast(half2v, w.z), acc, false);
    acc = __builtin_amdgcn_fdot2(__builtin_bit_cast(half2v, h.w),
                                 __builtin_bit_cast(half2v, w.w), acc, false);
#else
    const uint wv[4] = {w.x, w.y, w.z, w.w};
    const uint hv[4] = {h.x, h.y, h.z, h.w};
    #pragma unroll
    for (int j = 0; j < 4; ++j) {
        const __half2 wp = __builtin_bit_cast(__half2, wv[j]);
        const __half2 hp = __builtin_bit_cast(__half2, hv[j]);
        acc += __half2float(hp.x) * __half2float(wp.x);
        acc += __half2float(hp.y) * __half2float(wp.y);
    }
#endif
    return acc;
}

#define PIN4(v) asm("" : "+v"(v.x), "+v"(v.y), "+v"(v.z), "+v"(v.w))

// ---------------------------------------------------------------------------
// Sequential LSTM, one T-chunk. 64 blocks x 256 threads, 1 wave/SIMD
// (512-reg cap). Thread t owns hidden unit t: computes gates i,f,g,o for
// columns t, t+256, t+512, t+768, keeps c in a register, writes 1 f16 of h.
// One barrier per step via double-buffered h.
// ---------------------------------------------------------------------------
__global__
__attribute__((amdgpu_flat_work_group_size(256, 256)))
__attribute__((amdgpu_waves_per_eu(1, 1)))
void lstm_chunk(const float* __restrict__ xz, const uint4* __restrict__ P,
                const float* __restrict__ res, float* __restrict__ outseq,
                float* __restrict__ hstate, float* __restrict__ cstate,
                int t0)
{
    const int b = blockIdx.x;
    const int t = threadIdx.x;   // 0..255

    __shared__ __align__(16) uint4 hbuf[2][U_DIM / 8];   // 2 x 512 B packed f16 h
    __shared__ uint4 wlds[NG_LDS][G_DIM];                // 112 KB

    // ---- resident weights: 4 per-column arrays, constant-indexed ----
    uint4 w0[NG_REG], w1[NG_REG], w2[NG_REG], w3[NG_REG];
    #pragma unroll
    for (int g = 0; g < NG_REG; ++g) {
        w0[g] = P[(size_t)g * G_DIM + t];
        w1[g] = P[(size_t)g * G_DIM + t + 256];
        w2[g] = P[(size_t)g * G_DIM + t + 512];
        w3[g] = P[(size_t)g * G_DIM + t + 768];
    }
    #pragma unroll
    for (int g = 0; g < NG_REG; ++g) { PIN4(w0[g]); PIN4(w1[g]); PIN4(w2[g]); PIN4(w3[g]); }

    #pragma unroll
    for (int g = 0; g < NG_LDS; ++g) {
        const size_t base = (size_t)(NG_REG + g) * G_DIM;
        wlds[g][t      ] = P[base + t      ];
        wlds[g][t + 256] = P[base + t + 256];
        wlds[g][t + 512] = P[base + t + 512];
        wlds[g][t + 768] = P[base + t + 768];
    }

    float c;
    {
        float hv, cv;
        if (t0 == 0) { hv = 0.0f; cv = 0.0f; }
        else         { hv = hstate[b * U_DIM + t]; cv = cstate[b * U_DIM + t]; }
        c = cv;
        ((__half*)hbuf[0])[t] = __float2half_rn(hv);
    }
    __syncthreads();

    const float* __restrict__ xzb  = xz + (size_t)(b * TC) * G_DIM;
    const float* __restrict__ resb = res ? (res + (size_t)(b * T_DIM + t0) * U_DIM) : nullptr;
    float* __restrict__ outb       = outseq ? (outseq + (size_t)(b * T_DIM + t0) * U_DIM) : nullptr;

    float x0 = xzb[t], x1 = xzb[t + 256], x2 = xzb[t + 512], x3 = xzb[t + 768];
    float resv = resb ? resb[t] : 0.0f;

    int cur = 0;
    for (int tl = 0; tl < TC; ++tl) {
        float a0 = x0, a1 = x1, a2 = x2, a3 = x3;

        // issue streamed weight loads early (VMEM pipe; consumed last)
        uint4 s0[NG_STR], s1[NG_STR], s2[NG_STR], s3[NG_STR];
        #pragma unroll
        for (int g = 0; g < NG_STR; ++g) {
            const size_t base = (size_t)(NG_REG + NG_LDS + g) * G_DIM;
            s0[g] = P[base + t      ];
            s1[g] = P[base + t + 256];
            s2[g] = P[base + t + 512];
            s3[g] = P[base + t + 768];
        }

        // prefetch next step's xz / residual
        const int tn = (tl + 1 < TC) ? (tl + 1) : (TC - 1);
        x0 = xzb[(size_t)tn * G_DIM + t      ];
        x1 = xzb[(size_t)tn * G_DIM + t + 256];
        x2 = xzb[(size_t)tn * G_DIM + t + 512];
        x3 = xzb[(size_t)tn * G_DIM + t + 768];
        const float resn = resb ? resb[(size_t)tn * U_DIM + t] : 0.0f;

        const uint4* __restrict__ hp = hbuf[cur];

        // register-resident groups
        #pragma unroll
        for (int g = 0; g < NG_REG; ++g) {
            const uint4 h4 = hp[g];
            a0 = mac8(a0, w0[g], h4);
            a1 = mac8(a1, w1[g], h4);
            a2 = mac8(a2, w2[g], h4);
            a3 = mac8(a3, w3[g], h4);
        }
        // LDS-resident groups
        #pragma unroll
        for (int g = 0; g < NG_LDS; ++g) {
            const uint4 h4 = hp[NG_REG + g];
            a0 = mac8(a0, wlds[g][t      ], h4);
            a1 = mac8(a1, wlds[g][t + 256], h4);
            a2 = mac8(a2, wlds[g][t + 512], h4);
            a3 = mac8(a3, wlds[g][t + 768], h4);
        }
        // streamed groups
        #pragma unroll
        for (int g = 0; g < NG_STR; ++g) {
            const uint4 h4 = hp[NG_REG + NG_LDS + g];
            a0 = mac8(a0, s0[g], h4);
            a1 = mac8(a1, s1[g], h4);
            a2 = mac8(a2, s2[g], h4);
            a3 = mac8(a3, s3[g], h4);
        }

        // full gate set in-thread; c stays in a register
        const float iv = fsig(a0);
        const float fv = fsig(a1);
        const float gv = ftanh(a2);
        const float ov = fsig(a3);
        c = fv * c + iv * gv;
        const float hh = ov * ftanh(c);

        ((__half*)hbuf[cur ^ 1])[t] = __float2half_rn(hh);
        if (outb) outb[(size_t)tl * U_DIM + t] = hh + resv;
        resv = resn;
        cur ^= 1;
        __syncthreads();
    }

    hstate[b * U_DIM + t] = __half2float(((const __half*)hbuf[cur])[t]);
    cstate[b * U_DIM + t] = c;
}

// ---------------------------------------------------------------------------
// GEMM: out[m, :] = A[row(m), :] @ W + bias, for one T-chunk. (unchanged)
// ---------------------------------------------------------------------------
__global__ __launch_bounds__(256)
void gemm_proj(const float* __restrict__ A, const float* __restrict__ W,
               const float* __restrict__ bias, float* __restrict__ out,
               int t0)
{
    __shared__ float As[16][64];
    __shared__ float Bs[16][64];

    const int tid = threadIdx.x;
    const int bm = blockIdx.y * 64;
    const int bn = blockIdx.x * 64;

    const int arow = tid >> 2;
    const int acol = (tid & 3) << 2;
    const int m_local = bm + arow;
    const int b  = m_local >> 7;
    const int tl = m_local & (TC - 1);
    const float* arow_ptr = A + (size_t)(b * T_DIM + t0 + tl) * U_DIM;

    const int brow = tid >> 4;
    const int bcol = (tid & 15) << 2;

    const int tr = tid >> 4;
    const int tc = tid & 15;

    float acc[4][4] = {};

    for (int k0 = 0; k0 < U_DIM; k0 += 16) {
        const float4 a4 = *(const float4*)(arow_ptr + k0 + acol);
        const float4 b4 = *(const float4*)(W + (size_t)(k0 + brow) * G_DIM + bn + bcol);
        As[acol + 0][arow] = a4.x;
        As[acol + 1][arow] = a4.y;
        As[acol + 2][arow] = a4.z;
        As[acol + 3][arow] = a4.w;
        *(float4*)&Bs[brow][bcol] = b4;
        __syncthreads();
        #pragma unroll
        for (int k = 0; k < 16; ++k) {
            const float4 av = *(const float4*)&As[k][tr << 2];
            const float4 bv = *(const float4*)&Bs[k][tc << 2];
            const float a_[4] = {av.x, av.y, av.z, av.w};
            const float b_[4] = {bv.x, bv.y, bv.z, bv.w};
            #pragma unroll
            for (int i = 0; i < 4; ++i)
                #pragma unroll
                for (int j = 0; j < 4; ++j)
                    acc[i][j] += a_[i] * b_[j];
        }
        __syncthreads();
    }

    const int oc = bn + (tc << 2);
    const float4 bia = *(const float4*)(bias + oc);
    #pragma unroll
    for (int i = 0; i < 4; ++i) {
        const int m = bm + (tr << 2) + i;
        float4 o;
        o.x = acc[i][0] + bia.x;
        o.y = acc[i][1] + bia.y;
        o.z = acc[i][2] + bia.z;
        o.w = acc[i][3] + bia.w;
        *(float4*)(out + (size_t)m * G_DIM + oc) = o;
    }
}

// ---------------------------------------------------------------------------
// Final: y[b,o] = sum_j (h1[b,j] + h2[b, j%256]) * Wd[j,o] + bd[o]  (unchanged)
// ---------------------------------------------------------------------------
__global__ __launch_bounds__(256)
void final_proj(const float* __restrict__ h1, const float* __restrict__ h2,
                const float* __restrict__ Wd, const float* __restrict__ bd,
                float* __restrict__ y)
{
    const int b = blockIdx.x;
    const int tid = threadIdx.x;
    const int JTOT = T_DIM * U_DIM;   // 131072

    float a0 = 0.f, a1 = 0.f, a2 = 0.f, a3 = 0.f;
    const float* hb = h1 + (size_t)b * JTOT;
    const float* h2b = h2 + (size_t)b * U_DIM;

    for (int j = tid; j < JTOT; j += 256) {
        const float v = hb[j] + h2b[j & (U_DIM - 1)];
        const float4 w = *(const float4*)&Wd[(size_t)j * 4];
        a0 += v * w.x;
        a1 += v * w.y;
        a2 += v * w.z;
        a3 += v * w.w;
    }

    __shared__ float red[256][4];
    red[tid][0] = a0; red[tid][1] = a1; red[tid][2] = a2; red[tid][3] = a3;
    __syncthreads();
    for (int s = 128; s > 0; s >>= 1) {
        if (tid < s) {
            #pragma unroll
            for (int o = 0; o < 4; ++o) red[tid][o] += red[tid + s][o];
        }
        __syncthreads();
    }
    if (tid < 4) y[b * 4 + tid] = red[0][tid] + bd[tid];
}

// ---------------------------------------------------------------------------
extern "C" void kernel_launch(void* const* d_in, const int* in_sizes, int n_in,
                              void* d_out, int out_size, void* d_ws, size_t ws_size,
                              hipStream_t stream)
{
    (void)in_sizes; (void)n_in; (void)out_size; (void)ws_size;

    const float* x  = (const float*)d_in[0];
    const float* Wr = (const float*)d_in[1];
    const float* Ur = (const float*)d_in[2];
    const float* br = (const float*)d_in[3];
    const float* Wn = (const float*)d_in[4];
    const float* Un = (const float*)d_in[5];
    const float* bn = (const float*)d_in[6];
    const float* Wd = (const float*)d_in[7];
    const float* bd = (const float*)d_in[8];
    float* y = (float*)d_out;

    float* ws = (float*)d_ws;
    const size_t CHUNK_ELEMS = (size_t)B_DIM * TC * G_DIM;      // 8,388,608
    const size_t SEQ_ELEMS   = (size_t)B_DIM * T_DIM * U_DIM;   // 8,388,608
    const size_t BHID        = (size_t)B_DIM * U_DIM;           // 16,384
    float* xzbuf = ws;
    float* h0    = xzbuf + CHUNK_ELEMS;
    float* h1    = h0 + SEQ_ELEMS;
    float* hs    = h1 + SEQ_ELEMS;
    float* cs    = hs + BHID;
    uint4* Pr    = (uint4*)(cs + BHID);            // 32*1024 uint4 = 512 KB
    uint4* Pn    = Pr + (size_t)NG_TOT * G_DIM;    // 512 KB
    // total ws use ~= 97.2 MiB

    // ---- pack recurrent weights to f16 ----
    pack_w<<<128, 256, 0, stream>>>(Ur, Pr);
    pack_w<<<128, 256, 0, stream>>>(Un, Pn);

    dim3 ggrid(G_DIM / 64, (B_DIM * TC) / 64);   // (16, 128)

    // ---- layer 0: shared LSTM on x, no residual, outputs h0 ----
    for (int ch = 0; ch < NCHUNK; ++ch) {
        const int t0 = ch * TC;
        gemm_proj<<<ggrid, 256, 0, stream>>>(x, Wr, br, xzbuf, t0);
        lstm_chunk<<<B_DIM, 256, 0, stream>>>(xzbuf, Pr, nullptr, h0, hs, cs, t0);
    }
    // ---- layer 1: same shared weights on h0, residual add, outputs h1 ----
    for (int ch = 0; ch < NCHUNK; ++ch) {
        const int t0 = ch * TC;
        gemm_proj<<<ggrid, 256, 0, stream>>>(h0, Wr, br, xzbuf, t0);
        lstm_chunk<<<B_DIM, 256, 0, stream>>>(xzbuf, Pr, h0, h1, hs, cs, t0);
    }
    // ---- layer 2: Wn/Un/bn on h1, keep only last hidden state (in hs) ----
    for (int ch = 0; ch < NCHUNK; ++ch) {
        const int t0 = ch * TC;
        gemm_proj<<<ggrid, 256, 0, stream>>>(h1, Wn, bn, xzbuf, t0);
        lstm_chunk<<<B_DIM, 256, 0, stream>>>(xzbuf, Pn, nullptr, nullptr, hs, cs, t0);
    }
    // ---- final projection ----
    final_proj<<<B_DIM, 256, 0, stream>>>(h1, hs, Wd, bd, y);
}